// Round 2
// baseline (290.493 us; speedup 1.0000x reference)
//
#include <hip/hip_runtime.h>
#include <hip/hip_cooperative_groups.h>
#include <hip/hip_bf16.h>
#include <math.h>

#define LSEQ 32768
#define DMODEL 256
#define DHID 256
#define NCH 512                 // interleaved [re,im] hidden channels: col 2h=re, 2h+1=im
#define CHUNK 128
#define NCHUNKS (LSEQ / CHUNK)  // 256

namespace cg = cooperative_groups;

typedef __bf16 bf16_t;
typedef _Float16 f16_t;
typedef __bf16 bf16x8 __attribute__((ext_vector_type(8)));
typedef __bf16 bf16x4 __attribute__((ext_vector_type(4)));
typedef float f32x4 __attribute__((ext_vector_type(4)));

__device__ __forceinline__ void async_load16(const void* g, void* l) {
  __builtin_amdgcn_global_load_lds((__attribute__((address_space(1))) void*)g,
                                   (__attribute__((address_space(3))) void*)l,
                                   16, 0, 0);
}

__device__ __forceinline__ float f16tof(unsigned int u) {
  return (float)__builtin_bit_cast(_Float16, (unsigned short)(u & 0xffffu));
}
__device__ __forceinline__ unsigned int fTobf(float f) {
  return (unsigned int)__builtin_bit_cast(unsigned short, (bf16_t)f);
}

// ---- prep: lam[row*DHID+h] table, all powers computed in fp64 --------------
// rows: 0,1 = lambda; 2,3 = lambda^128; 4,5 = lambda^64; 6+2j,7+2j = lambda^(128*2^j)
__global__ void prep_params(const float* __restrict__ nu_log,
                            const float* __restrict__ theta_log,
                            float* __restrict__ lam) {
  int h = threadIdx.x;
  if (h >= DHID) return;
  double nu = exp((double)nu_log[h]);
  double th = exp((double)theta_log[h]);
#define PUT(row, n) { \
    double mag = exp(-(double)(n) * nu); \
    double ph  = fmod((double)(n) * th, 6.283185307179586); \
    lam[(row) * DHID + h]     = (float)(mag * cos(ph)); \
    lam[((row)+1) * DHID + h] = (float)(mag * sin(ph)); }
  PUT(0, 1.0)
  PUT(2, 128.0)
  PUT(4, 64.0)
  for (int j = 0; j < 8; ++j) PUT(6 + 2 * j, 128.0 * (double)(1 << j))
#undef PUT
}

// W1[n][k], n interleaved: n=2h -> B_re[h][k]*gamma[h]; n=2h+1 -> B_im[h][k]*gamma[h]
__global__ void pack_w1(const float* __restrict__ B_re, const float* __restrict__ B_im,
                        const float* __restrict__ gamma_log, bf16_t* __restrict__ W1) {
  int n = blockIdx.x, k = threadIdx.x;
  int h = n >> 1;
  float g = expf(gamma_log[h]);
  float v = (((n & 1) == 0) ? B_re[h * DMODEL + k] : B_im[h * DMODEL + k]) * g;
  W1[n * DMODEL + k] = (bf16_t)v;
}

// W2[m][k], k interleaved: k=2h -> C_re[m][h]; k=2h+1 -> -C_im[m][h]
__global__ void pack_w2(const float* __restrict__ C_re, const float* __restrict__ C_im,
                        bf16_t* __restrict__ W2) {
  int m = blockIdx.x, k = threadIdx.x;  // 512 threads
  int h = k >> 1;
  float v = ((k & 1) == 0) ? C_re[m * DHID + h] : -C_im[m * DHID + h];
  W2[m * NCH + k] = (bf16_t)v;
}

__global__ void convert_x(const float* __restrict__ x, bf16_t* __restrict__ xb) {
  int i = blockIdx.x * 256 + threadIdx.x;
  float4 v = ((const float4*)x)[i];
  bf16x4 o = {(bf16_t)v.x, (bf16_t)v.y, (bf16_t)v.z, (bf16_t)v.w};
  ((bf16x4*)xb)[i] = o;
}

// ---- fused cooperative kernel: GEMM1 -> local scan -> grid sync -> lookback
//      -> carry scan (LDS-resident) -> GEMM2 + D-fuse. One block per chunk. --
__global__ __launch_bounds__(512, 2) void lru_fused(
    const bf16_t* __restrict__ A,    // xb [L][256]
    const bf16_t* __restrict__ W1,   // [512][256]
    const bf16_t* __restrict__ W2,   // [256][512]
    const float* __restrict__ lam,
    float* __restrict__ E,           // [NCHUNKS][512] interleaved (re,im) pairs
    const float* __restrict__ X, const float* __restrict__ Dv,
    float* __restrict__ out) {
  __shared__ __align__(16) char smem[151552];          // 148 KB
  char*   H   = smem;                                  // [128][1024B] swizzled pairs
  bf16_t* As  = (bf16_t*)smem;                         // [128][32] (aliases H, GEMM1 only)
  bf16_t* Bs  = (bf16_t*)(smem + 8192);                // [512][32] (aliases H, GEMM1 only)
  bf16_t* Bs2 = (bf16_t*)(smem + 131072);              // [256][32] (GEMM2 staging)
  float*  Ep  = (float*)(smem + 147456);               // [2][256][2] f32

  const int tid = threadIdx.x;
  const int c = blockIdx.x;
  const int r0 = c * CHUNK;
  const int wave = tid >> 6, lane = tid & 63;
  const int wm = wave & 1, wn = wave >> 1;
  const int lrow = lane & 15, lk = lane >> 4;

  // ---------------- Phase A: GEMM1, full width 128x512, K=256 ----------------
  f32x4 acc[4][8] = {};
  for (int k0 = 0; k0 < DMODEL; k0 += 32) {
    __syncthreads();
    async_load16(A + (size_t)(r0 + (tid >> 2)) * DMODEL + k0 + (tid & 3) * 8,
                 (char*)As + tid * 16);
#pragma unroll
    for (int it = 0; it < 4; ++it) {
      int idx = it * 512 + tid;
      async_load16(W1 + (size_t)(idx >> 2) * DMODEL + k0 + (idx & 3) * 8,
                   (char*)Bs + idx * 16);
    }
    __syncthreads();
    bf16x8 af[4], bfr[8];
#pragma unroll
    for (int i = 0; i < 4; ++i)
      af[i] = *(const bf16x8*)(As + (wm * 64 + i * 16 + lrow) * 32 + lk * 8);
#pragma unroll
    for (int j = 0; j < 8; ++j)
      bfr[j] = *(const bf16x8*)(Bs + (wn * 128 + j * 16 + lrow) * 32 + lk * 8);
#pragma unroll
    for (int i = 0; i < 4; ++i)
#pragma unroll
      for (int j = 0; j < 8; ++j)
        acc[i][j] = __builtin_amdgcn_mfma_f32_16x16x32_bf16(af[i], bfr[j], acc[i][j], 0, 0, 0);
  }
  __syncthreads();  // frag reads done; As/Bs region becomes H

  // ---------------- Phase B: acc -> H (fp16 pairs, swizzled) -----------------
#pragma unroll
  for (int i = 0; i < 4; ++i)
#pragma unroll
    for (int r = 0; r < 4; ++r) {
      int row = wm * 64 + i * 16 + lk * 4 + r;
      int key = (row & 7) << 4;
#pragma unroll
      for (int j = 0; j < 8; ++j) {
        int col = wn * 128 + j * 16 + lrow;
        *(f16_t*)(H + row * 1024 + ((col * 2) ^ key)) = (f16_t)acc[i][j][r];
      }
    }
  __syncthreads();

  // ---------------- Phase C: local end-state E_c (2 segs x 64 + Horner) ------
  {
    int p = tid & 255, seg = tid >> 8;
    float lre = lam[p], lim = lam[DHID + p];
    float sre = 0.f, sim = 0.f;
    int cb = 4 * p;
#pragma unroll 4
    for (int t = 0; t < 64; ++t) {
      int row = seg * 64 + t;
      unsigned int w = *(const unsigned int*)(H + row * 1024 + (cb ^ ((row & 7) << 4)));
      float bre = f16tof(w), bim = f16tof(w >> 16);
      float nre = fmaf(lre, sre, fmaf(-lim, sim, bre));
      float nim = fmaf(lre, sim, fmaf(lim, sre, bim));
      sre = nre; sim = nim;
    }
    Ep[seg * 512 + 2 * p]     = sre;
    Ep[seg * 512 + 2 * p + 1] = sim;
  }
  __syncthreads();
  if (tid < 256) {
    int p = tid;
    float ar = lam[4 * DHID + p], ai = lam[5 * DHID + p];  // lambda^64
    float s0r = Ep[2 * p], s0i = Ep[2 * p + 1];
    float s1r = Ep[512 + 2 * p], s1i = Ep[512 + 2 * p + 1];
    float er = fmaf(ar, s0r, fmaf(-ai, s0i, s1r));
    float ei = fmaf(ar, s0i, fmaf(ai, s0r, s1i));
    E[(size_t)c * NCH + 2 * p]     = er;
    E[(size_t)c * NCH + 2 * p + 1] = ei;
  }
  __threadfence();
  cg::this_grid().sync();
  __threadfence();

  // ---------------- Phase D: lookback carry = sum_k lamC^{c-1-k} E_k ---------
  float carR = 0.f, carI = 0.f;
  {
    int p = tid & 255, hi = tid >> 8;
    int half = c >> 1;
    int lo = hi ? half : 0;
    int hiEnd = hi ? c : half;
    float aR = lam[2 * DHID + p], aI = lam[3 * DHID + p];  // lambda^128
    float sr = 0.f, si = 0.f;
#pragma unroll 4
    for (int k = lo; k < hiEnd; ++k) {
      float2 e = *(const float2*)(E + (size_t)k * NCH + 2 * p);
      float nr = fmaf(aR, sr, fmaf(-aI, si, e.x));
      float ni = fmaf(aR, si, fmaf(aI, sr, e.y));
      sr = nr; si = ni;
    }
    Ep[hi * 512 + 2 * p]     = sr;
    Ep[hi * 512 + 2 * p + 1] = si;
  }
  __syncthreads();
  if (tid < 256) {
    int p = tid;
    int lenb = c - (c >> 1);
    float pr = 1.f, pi = 0.f;  // lamC^lenb via fp64-accurate power-of-two table
#pragma unroll
    for (int j = 0; j < 8; ++j)
      if (lenb & (1 << j)) {
        float br = lam[(6 + 2 * j) * DHID + p], bi = lam[(7 + 2 * j) * DHID + p];
        float nr = pr * br - pi * bi;
        float ni = pr * bi + pi * br;
        pr = nr; pi = ni;
      }
    float sar = Ep[2 * p], sai = Ep[2 * p + 1];
    float sbr = Ep[512 + 2 * p], sbi = Ep[512 + 2 * p + 1];
    carR = fmaf(pr, sar, fmaf(-pi, sai, sbr));
    carI = fmaf(pr, sai, fmaf(pi, sar, sbi));
  }
  __syncthreads();

  // ---------------- Phase E: in-place carry scan of H (fp16 -> bf16) ---------
  if (tid < 256) {
    int p = tid;
    float lre = lam[p], lim = lam[DHID + p];
    float sre = carR, sim = carI;
    int cb = 4 * p;
#pragma unroll 4
    for (int t = 0; t < CHUNK; ++t) {
      unsigned int* ptr = (unsigned int*)(H + t * 1024 + (cb ^ ((t & 7) << 4)));
      unsigned int w = *ptr;
      float bre = f16tof(w), bim = f16tof(w >> 16);
      float nre = fmaf(lre, sre, fmaf(-lim, sim, bre));
      float nim = fmaf(lre, sim, fmaf(lim, sre, bim));
      sre = nre; sim = nim;
      *ptr = (fTobf(sim) << 16) | fTobf(sre);
    }
  }

  // ---------------- Phase F: GEMM2 out = H @ W2^T + X*D ----------------------
  f32x4 acc2[4][4] = {};
  for (int k0 = 0; k0 < NCH; k0 += 32) {
    __syncthreads();
#pragma unroll
    for (int it = 0; it < 2; ++it) {
      int idx = it * 512 + tid;
      async_load16(W2 + (size_t)(idx >> 2) * NCH + k0 + (idx & 3) * 8,
                   (char*)Bs2 + idx * 16);
    }
    __syncthreads();
    bf16x8 af2[4], bf2[4];
#pragma unroll
    for (int i = 0; i < 4; ++i) {
      int m = wm * 64 + i * 16 + lrow;
      af2[i] = *(const bf16x8*)(H + m * 1024 + ((2 * k0 + lk * 16) ^ ((m & 7) << 4)));
    }
#pragma unroll
    for (int j = 0; j < 4; ++j)
      bf2[j] = *(const bf16x8*)(Bs2 + (wn * 64 + j * 16 + lrow) * 32 + lk * 8);
#pragma unroll
    for (int i = 0; i < 4; ++i)
#pragma unroll
      for (int j = 0; j < 4; ++j)
        acc2[i][j] = __builtin_amdgcn_mfma_f32_16x16x32_bf16(af2[i], bf2[j], acc2[i][j], 0, 0, 0);
  }

#pragma unroll
  for (int i = 0; i < 4; ++i)
#pragma unroll
    for (int r = 0; r < 4; ++r) {
      int row = r0 + wm * 64 + i * 16 + lk * 4 + r;
#pragma unroll
      for (int j = 0; j < 4; ++j) {
        int col = wn * 64 + j * 16 + lrow;
        float v = acc2[i][j][r] + X[(size_t)row * DMODEL + col] * Dv[col];
        out[(size_t)row * DMODEL + col] = v;
      }
    }
}

extern "C" void kernel_launch(void* const* d_in, const int* in_sizes, int n_in,
                              void* d_out, int out_size, void* d_ws, size_t ws_size,
                              hipStream_t stream) {
  const float* inputs    = (const float*)d_in[0];
  const float* nu_log    = (const float*)d_in[1];
  const float* theta_log = (const float*)d_in[2];
  const float* gamma_log = (const float*)d_in[3];
  const float* B_re      = (const float*)d_in[4];
  const float* B_im      = (const float*)d_in[5];
  const float* C_re      = (const float*)d_in[6];
  const float* C_im      = (const float*)d_in[7];
  const float* Dvec      = (const float*)d_in[8];
  float* out = (float*)d_out;

  char* w = (char*)d_ws;
  bf16_t* W1 = (bf16_t*)w; w += (size_t)NCH * DMODEL * 2;   // 256 KB
  bf16_t* W2 = (bf16_t*)w; w += (size_t)DMODEL * NCH * 2;   // 256 KB
  float* lam = (float*)w;  w += 24576;                      // 22*DHID floats used
  bf16_t* xb = (bf16_t*)w; w += (size_t)LSEQ * DMODEL * 2;  // 16 MB
  float* E   = (float*)w;  w += (size_t)NCHUNKS * NCH * 4;  // 512 KB

  prep_params<<<1, 256, 0, stream>>>(nu_log, theta_log, lam);
  pack_w1<<<NCH, DMODEL, 0, stream>>>(B_re, B_im, gamma_log, W1);
  pack_w2<<<DMODEL, NCH, 0, stream>>>(C_re, C_im, W2);
  convert_x<<<(LSEQ * DMODEL) / 4 / 256, 256, 0, stream>>>(inputs, xb);

  void* args[] = {&xb, &W1, &W2, &lam, &E, &inputs, &Dvec, &out};
  hipLaunchCooperativeKernel((const void*)lru_fused, dim3(NCHUNKS), dim3(512),
                             args, 0, stream);
}

// Round 4
// 157.117 us; speedup vs baseline: 1.8489x; 1.8489x over previous
//
#include <hip/hip_runtime.h>
#include <hip/hip_bf16.h>
#include <math.h>

#define LSEQ 32768
#define DMODEL 256
#define DHID 256
#define NCH 512                 // interleaved [re,im] hidden channels: col 2h=re, 2h+1=im
#define CHUNK 128
#define NCHUNKS (LSEQ / CHUNK)  // 256

typedef __bf16 bf16_t;
typedef _Float16 f16_t;
typedef __bf16 bf16x8 __attribute__((ext_vector_type(8)));
typedef __bf16 bf16x4 __attribute__((ext_vector_type(4)));
typedef float f32x4 __attribute__((ext_vector_type(4)));

__device__ __forceinline__ void async_load16(const void* g, void* l) {
  __builtin_amdgcn_global_load_lds((__attribute__((address_space(1))) void*)g,
                                   (__attribute__((address_space(3))) void*)l,
                                   16, 0, 0);
}

__device__ __forceinline__ float f16tof(unsigned int u) {
  return (float)__builtin_bit_cast(_Float16, (unsigned short)(u & 0xffffu));
}
__device__ __forceinline__ unsigned int fTobf(float f) {
  return (unsigned int)__builtin_bit_cast(unsigned short, (bf16_t)f);
}

// ---- fused prep: params + W1 + W2 + x->bf16, one launch ---------------------
// lam rows: 0,1 = lambda; 2,3 = lambda^32; 4+2j,5+2j (j=0..7) = lambda^(128*2^j)
__global__ void prep_all(const float* __restrict__ nu_log,
                         const float* __restrict__ theta_log,
                         const float* __restrict__ gamma_log,
                         const float* __restrict__ B_re, const float* __restrict__ B_im,
                         const float* __restrict__ C_re, const float* __restrict__ C_im,
                         const float* __restrict__ x,
                         float* __restrict__ lam, bf16_t* __restrict__ W1,
                         bf16_t* __restrict__ W2, bf16_t* __restrict__ xb) {
  const int bid = blockIdx.x, tid = threadIdx.x;
  if (bid == 0) {
    int h = tid;
    if (h < DHID) {
      double nu = exp((double)nu_log[h]);
      double th = exp((double)theta_log[h]);
#define PUT(row, n) { \
      double mag = exp(-(double)(n) * nu); \
      double ph  = fmod((double)(n) * th, 6.283185307179586); \
      lam[(row) * DHID + h]     = (float)(mag * cos(ph)); \
      lam[((row)+1) * DHID + h] = (float)(mag * sin(ph)); }
      PUT(0, 1.0)
      PUT(2, 32.0)
      for (int j = 0; j < 8; ++j) PUT(4 + 2 * j, 128.0 * (double)(1 << j))
#undef PUT
    }
  } else if (bid < 513) {
    // W1[n][k], n interleaved: n=2h -> B_re[h][k]*g; n=2h+1 -> B_im[h][k]*g
    int n = bid - 1, k = tid, h = n >> 1;
    float g = expf(gamma_log[h]);
    float v = (((n & 1) == 0) ? B_re[h * DMODEL + k] : B_im[h * DMODEL + k]) * g;
    W1[n * DMODEL + k] = (bf16_t)v;
  } else if (bid < 1025) {
    // W2[m][k], k interleaved: k=2h -> C_re[m][h]; k=2h+1 -> -C_im[m][h]
    int idx = bid - 513;
    int m = idx >> 1, k = (idx & 1) * 256 + tid, h = k >> 1;
    float v = ((k & 1) == 0) ? C_re[m * DHID + h] : -C_im[m * DHID + h];
    W2[m * NCH + k] = (bf16_t)v;
  } else {
    int i = (bid - 1025) * 256 + tid;  // over LSEQ*DMODEL/4 float4s
    float4 v = ((const float4*)x)[i];
    bf16x4 o = {(bf16_t)v.x, (bf16_t)v.y, (bf16_t)v.z, (bf16_t)v.w};
    ((bf16x4*)xb)[i] = o;
  }
}

// ---------------- kernel A: GEMM1 (chunk tile) + fp16 Bu store + chunk E ----
// grid (2, NCHUNKS), 512 threads. Tile 128(t) x 256(ch), K=256. 68 KB LDS.
// Bu global layout: [L][1024B] fp16, byte cb stored at cb ^ ((t&7)<<4).
// E[c][512]: interleaved (re,im) pairs, per-128-row chunk end state.
__global__ __launch_bounds__(512) void gemm1_scan(
    const bf16_t* __restrict__ A, const bf16_t* __restrict__ Bw,
    f16_t* __restrict__ Bu, const float* __restrict__ lam,
    float* __restrict__ E) {
  __shared__ __align__(16) char smem[69632];  // 68 KB
  bf16_t* As = (bf16_t*)smem;                 // [128][32] bf16 = 8 KB
  bf16_t* Bs = (bf16_t*)(smem + 8192);        // [256][32] bf16 = 16 KB
  char*   Bt = smem;                          // [128][512B] fp16 swizzled (aliases As/Bs)
  float*  Ep = (float*)(smem + 65536);        // [4][128][2] f32 = 4 KB

  const int tid = threadIdx.x;
  const int gx = blockIdx.x;          // channel half: pairs [gx*128, gx*128+128)
  const int c  = blockIdx.y;          // chunk
  const int r0 = c * CHUNK;
  const int c0 = gx * 256;            // column offset into the 512-wide Bu
  const int wave = tid >> 6, lane = tid & 63;
  const int wm = wave & 1, wn = wave >> 1;
  const int lrow = lane & 15, lk = lane >> 4;
  const int ra = tid >> 2, ka = (tid & 3) * 8;

  f32x4 acc[4][4] = {};

  for (int k0 = 0; k0 < DMODEL; k0 += 32) {
    __syncthreads();
    async_load16(A + (size_t)(r0 + ra) * DMODEL + k0 + ka, (char*)As + tid * 16);
    async_load16(Bw + (size_t)(c0 + ra) * DMODEL + k0 + ka, (char*)Bs + tid * 16);
    async_load16(Bw + (size_t)(c0 + 128 + ra) * DMODEL + k0 + ka,
                 (char*)Bs + 8192 + tid * 16);
    __syncthreads();
    bf16x8 af[4], bfr[4];
#pragma unroll
    for (int i = 0; i < 4; ++i)
      af[i] = *(const bf16x8*)(As + (wm * 64 + i * 16 + lrow) * 32 + lk * 8);
#pragma unroll
    for (int j = 0; j < 4; ++j)
      bfr[j] = *(const bf16x8*)(Bs + (wn * 64 + j * 16 + lrow) * 32 + lk * 8);
#pragma unroll
    for (int i = 0; i < 4; ++i)
#pragma unroll
      for (int j = 0; j < 4; ++j)
        acc[i][j] = __builtin_amdgcn_mfma_f32_16x16x32_bf16(af[i], bfr[j], acc[i][j], 0, 0, 0);
  }
  __syncthreads();  // all frag reads done before overwriting As/Bs with Bt

  // acc -> Bt (fp16, swizzled local half-rows of 512B)
#pragma unroll
  for (int i = 0; i < 4; ++i)
#pragma unroll
    for (int r = 0; r < 4; ++r) {
      int row = wm * 64 + i * 16 + lk * 4 + r;
      int key = (row & 7) << 4;
#pragma unroll
      for (int j = 0; j < 4; ++j) {
        int col = wn * 64 + j * 16 + lrow;
        *(f16_t*)(Bt + row * 512 + ((col * 2) ^ key)) = (f16_t)acc[i][j][r];
      }
    }
  __syncthreads();

  // Bt -> global Bu (byte-identical image; (r0+row)&7 == row&7 since r0%128==0)
  char* dst = (char*)Bu + (size_t)r0 * 1024 + gx * 512;
#pragma unroll
  for (int it = 0; it < 8; ++it) {
    int idx = it * 512 + tid;
    int row = idx >> 5, off = (idx & 31) * 16;
    *(f32x4*)(dst + (size_t)row * 1024 + off) = *(const f32x4*)(Bt + row * 512 + off);
  }

  // local end-states: 4 time segments of 32 rows per channel pair
  {
    int p = tid & 127, seg = tid >> 7;
    int h = gx * 128 + p;
    float lre = lam[h], lim = lam[DHID + h];
    float sre = 0.f, sim = 0.f;
    int cb = 4 * p;
#pragma unroll 4
    for (int t = 0; t < 32; ++t) {
      int row = seg * 32 + t;
      unsigned int w = *(const unsigned int*)(Bt + row * 512 + (cb ^ ((row & 7) << 4)));
      float bre = f16tof(w), bim = f16tof(w >> 16);
      float nre = fmaf(lre, sre, fmaf(-lim, sim, bre));
      float nim = fmaf(lre, sim, fmaf(lim, sre, bim));
      sre = nre; sim = nim;
    }
    Ep[seg * 256 + 2 * p]     = sre;
    Ep[seg * 256 + 2 * p + 1] = sim;
  }
  __syncthreads();
  // Horner combine of 4 segments with lambda^32 -> chunk end state E_c
  if (tid < 128) {
    int p = tid, h = gx * 128 + p;
    float ar = lam[2 * DHID + h], ai = lam[3 * DHID + h];  // lambda^32
    float er = Ep[2 * p], ei = Ep[2 * p + 1];
#pragma unroll
    for (int s = 1; s < 4; ++s) {
      float tr = fmaf(ar, er, fmaf(-ai, ei, Ep[s * 256 + 2 * p]));
      float ti = fmaf(ar, ei, fmaf(ai, er, Ep[s * 256 + 2 * p + 1]));
      er = tr; ei = ti;
    }
    E[(size_t)c * NCH + 2 * h]     = er;
    E[(size_t)c * NCH + 2 * h + 1] = ei;
  }
}

// ---------------- kernel B: stage chunk H -> lookback carry -> scan -> GEMM2
// grid NCHUNKS, 512 threads, 144 KB LDS (1 block/CU). Carry for chunk c is
// derived in-kernel from E[0..c-1] (lambda^128 Horner, two halves + bit-table
// combine) while the 128 KB H DMA is in flight. Tail-first block order.
__global__ __launch_bounds__(512) void scan_gemm2(
    const f16_t* __restrict__ Bu, const bf16_t* __restrict__ W2,
    const float* __restrict__ lam, const float* __restrict__ E,
    const float* __restrict__ X, const float* __restrict__ Dv,
    float* __restrict__ out) {
  __shared__ __align__(16) char smem[147456];
  char*   H  = smem;                          // [128][1024B] swizzled pairs
  bf16_t* Bs = (bf16_t*)(smem + 131072);      // [256][32] bf16 = 16 KB (GEMM phase)
  float*  Ep = (float*)(smem + 131072);       // aliases Bs; used pre-GEMM only

  const int tid = threadIdx.x;
  const int c = (int)gridDim.x - 1 - (int)blockIdx.x;  // tail-first
  const int r0 = c * CHUNK;

  // issue 128 KB H staging (linear; global image == swizzled LDS image)
  const char* src = (const char*)Bu + (size_t)r0 * 1024;
#pragma unroll
  for (int it = 0; it < 16; ++it)
    async_load16(src + it * 8192 + tid * 16, H + it * 8192 + tid * 16);

  // lookback partials over E[0..c-1] (overlapped with the DMA above)
  {
    int p = tid & 255, half = tid >> 8;
    int m = c >> 1;
    int lo = half ? m : 0, end = half ? c : m;
    float aR = lam[4 * DHID + p], aI = lam[5 * DHID + p];  // lambda^128
    float sr = 0.f, si = 0.f;
#pragma unroll 4
    for (int k = lo; k < end; ++k) {
      float2 e = *(const float2*)(E + (size_t)k * NCH + 2 * p);
      float nr = fmaf(aR, sr, fmaf(-aI, si, e.x));
      float ni = fmaf(aR, si, fmaf(aI, sr, e.y));
      sr = nr; si = ni;
    }
    Ep[half * 512 + 2 * p]     = sr;
    Ep[half * 512 + 2 * p + 1] = si;
  }
  __syncthreads();  // partials visible; H DMA drained

  if (tid < 256) {
    int p = tid;
    int lenb = c - (c >> 1);
    float pr = 1.f, pi = 0.f;  // lambda^(128*lenb) via fp64-accurate bit table
#pragma unroll
    for (int j = 0; j < 8; ++j)
      if (lenb & (1 << j)) {
        float br = lam[(4 + 2 * j) * DHID + p], bi = lam[(5 + 2 * j) * DHID + p];
        float nr = pr * br - pi * bi, ni = pr * bi + pi * br;
        pr = nr; pi = ni;
      }
    float sar = Ep[2 * p], sai = Ep[2 * p + 1];
    float sbr = Ep[512 + 2 * p], sbi = Ep[512 + 2 * p + 1];
    float carR = fmaf(pr, sar, fmaf(-pi, sai, sbr));
    float carI = fmaf(pr, sai, fmaf(pi, sar, sbi));

    // in-place carry scan of H (fp16 in -> bf16 state out, same slot)
    float lre = lam[p], lim = lam[DHID + p];
    float sre = carR, sim = carI;
    int cb = 4 * p;
#pragma unroll 4
    for (int t = 0; t < CHUNK; ++t) {
      unsigned int* ptr = (unsigned int*)(H + t * 1024 + (cb ^ ((t & 7) << 4)));
      unsigned int w = *ptr;
      float bre = f16tof(w), bim = f16tof(w >> 16);
      float nre = fmaf(lre, sre, fmaf(-lim, sim, bre));
      float nim = fmaf(lre, sim, fmaf(lim, sre, bim));
      sre = nre; sim = nim;
      *ptr = (fTobf(sim) << 16) | fTobf(sre);
    }
  }

  // GEMM2: out[128 x 256] = H[128 x 512] @ W2[256 x 512]^T + X*D
  const int wave = tid >> 6, lane = tid & 63;
  const int wm = wave & 1, wn = wave >> 1;
  const int lrow = lane & 15, lk = lane >> 4;
  const int ra = tid >> 2, ka = (tid & 3) * 8;
  f32x4 acc[4][4] = {};
  for (int k0 = 0; k0 < NCH; k0 += 32) {
    __syncthreads();  // first iter: scan done + Ep reads done before Bs overwrite
#pragma unroll
    for (int it = 0; it < 2; ++it) {
      int idx = it * 512 + tid;
      async_load16(W2 + (size_t)(idx >> 2) * NCH + k0 + (idx & 3) * 8,
                   (char*)Bs + idx * 16);
    }
    __syncthreads();
    bf16x8 af[4], bfr[4];
#pragma unroll
    for (int i = 0; i < 4; ++i) {
      int m = wm * 64 + i * 16 + lrow;
      af[i] = *(const bf16x8*)(H + m * 1024 + ((2 * k0 + lk * 16) ^ ((m & 7) << 4)));
    }
#pragma unroll
    for (int j = 0; j < 4; ++j)
      bfr[j] = *(const bf16x8*)(Bs + (wn * 64 + j * 16 + lrow) * 32 + lk * 8);
#pragma unroll
    for (int i = 0; i < 4; ++i)
#pragma unroll
      for (int j = 0; j < 4; ++j)
        acc[i][j] = __builtin_amdgcn_mfma_f32_16x16x32_bf16(af[i], bfr[j], acc[i][j], 0, 0, 0);
  }

#pragma unroll
  for (int i = 0; i < 4; ++i)
#pragma unroll
    for (int r = 0; r < 4; ++r) {
      int row = r0 + wm * 64 + i * 16 + lk * 4 + r;
#pragma unroll
      for (int j = 0; j < 4; ++j) {
        int col = wn * 64 + j * 16 + lrow;
        float v = acc[i][j][r] + X[(size_t)row * DMODEL + col] * Dv[col];
        out[(size_t)row * DMODEL + col] = v;
      }
    }
}

extern "C" void kernel_launch(void* const* d_in, const int* in_sizes, int n_in,
                              void* d_out, int out_size, void* d_ws, size_t ws_size,
                              hipStream_t stream) {
  const float* inputs    = (const float*)d_in[0];
  const float* nu_log    = (const float*)d_in[1];
  const float* theta_log = (const float*)d_in[2];
  const float* gamma_log = (const float*)d_in[3];
  const float* B_re      = (const float*)d_in[4];
  const float* B_im      = (const float*)d_in[5];
  const float* C_re      = (const float*)d_in[6];
  const float* C_im      = (const float*)d_in[7];
  const float* Dvec      = (const float*)d_in[8];
  float* out = (float*)d_out;

  char* w = (char*)d_ws;
  bf16_t* W1 = (bf16_t*)w; w += (size_t)NCH * DMODEL * 2;   // 256 KB
  bf16_t* W2 = (bf16_t*)w; w += (size_t)DMODEL * NCH * 2;   // 256 KB
  float* lam = (float*)w;  w += 24576;                      // 20 rows used
  bf16_t* xb = (bf16_t*)w; w += (size_t)LSEQ * DMODEL * 2;  // 16 MB
  f16_t* Bu  = (f16_t*)w;  w += (size_t)LSEQ * NCH * 2;     // 32 MB
  float* E   = (float*)w;  w += (size_t)NCHUNKS * NCH * 4;  // 512 KB

  // grid: 1 (params) + 512 (W1) + 512 (W2) + 8192 (convert) = 9217
  prep_all<<<9217, 256, 0, stream>>>(nu_log, theta_log, gamma_log,
                                     B_re, B_im, C_re, C_im, inputs,
                                     lam, W1, W2, xb);
  gemm1_scan<<<dim3(2, NCHUNKS), 512, 0, stream>>>(xb, W1, Bu, lam, E);
  scan_gemm2<<<NCHUNKS, 512, 0, stream>>>(Bu, W2, lam, E, inputs, Dvec, out);
}